// Round 8
// baseline (596.070 us; speedup 1.0000x reference)
//
#include <hip/hip_runtime.h>
#include <hip/hip_fp16.h>

#define NNODES 50000
#define NEDGES 800000
#define ETOT   (NNODES + NEDGES)   // 850000 edges incl. self-loops
#define NH     8
#define HID    64
#define D1     512                  // NH*HID
#define INC    512
#define OUTC   128
#define NEG    0.2f
#define MPAD   50048                // 391*128, padded row count for GEMM tiles

typedef __attribute__((ext_vector_type(8))) short short8;
typedef __attribute__((ext_vector_type(4))) float f32x4;
typedef _Float16 half8v __attribute__((ext_vector_type(8)));
typedef _Float16 half2v __attribute__((ext_vector_type(2)));

__device__ __forceinline__ ushort f2h_bits(float x) {
    _Float16 h = (_Float16)x; return __builtin_bit_cast(ushort, h);
}
__device__ __forceinline__ float h2f(ushort b) {
    return (float)__builtin_bit_cast(_Float16, b);
}
__device__ __forceinline__ uint splat_h2(float p) {
    uint b = (uint)f2h_bits(p); return b | (b << 16);
}
__device__ __forceinline__ half2v as_h2(uint u) { return __builtin_bit_cast(half2v, u); }
__device__ __forceinline__ float leaky(float v) { return v >= 0.f ? v : NEG * v; }

// ---------------- CSR build ----------------
__global__ void count_deg(const int* __restrict__ ei, int* __restrict__ deg) {
    int i = blockIdx.x * 256 + threadIdx.x;
    if (i >= ETOT) return;
    int dst = (i < NEDGES) ? ei[NEDGES + i] : (i - NEDGES);
    atomicAdd(&deg[dst], 1);
}

__global__ void scan_deg(const int* __restrict__ deg, int* __restrict__ rs) {
    __shared__ int part[1024];
    const int n = NNODES;
    const int CH = (n + 1023) / 1024;
    int t = threadIdx.x;
    int lo = t * CH, hi = min(lo + CH, n);
    int s = 0;
    for (int i = lo; i < hi; ++i) s += deg[i];
    part[t] = s;
    __syncthreads();
    for (int off = 1; off < 1024; off <<= 1) {
        int v = (t >= off) ? part[t - off] : 0;
        __syncthreads();
        part[t] += v;
        __syncthreads();
    }
    int run = (t == 0) ? 0 : part[t - 1];
    for (int i = lo; i < hi; ++i) { rs[i] = run; run += deg[i]; }
    if (hi == n) rs[n] = run;
}

__global__ void scatter_edges(const int* __restrict__ ei, int* __restrict__ cursor,
                              int* __restrict__ csr_src) {
    int i = blockIdx.x * 256 + threadIdx.x;
    if (i >= ETOT) return;
    int src, dst;
    if (i < NEDGES) { src = ei[i]; dst = ei[NEDGES + i]; }
    else            { src = dst = i - NEDGES; }
    int pos = atomicAdd(&cursor[dst], 1);
    csr_src[pos] = src;
}

// ---------------- dtype prep (f16) ----------------
__global__ void cast_f16(const float* __restrict__ x, ushort* __restrict__ xh, int n4) {
    int i = blockIdx.x * 256 + threadIdx.x;
    if (i >= n4) return;
    float4 v = *(const float4*)&x[(size_t)i * 4];
    ushort4 o = { f2h_bits(v.x), f2h_bits(v.y), f2h_bits(v.z), f2h_bits(v.w) };
    *(ushort4*)&xh[(size_t)i * 4] = o;
}

// WT[n][k] = W[k][n], f16 out.
__global__ void cast_wT(const float* __restrict__ W, ushort* __restrict__ WT, int K, int N) {
    int idx = blockIdx.x * 256 + threadIdx.x;
    if (idx >= K * N) return;
    int n = idx / K, k = idx - n * K;
    WT[idx] = f2h_bits(W[(size_t)k * N + n]);
}

// ---------------- layer-1 GEMM (128x128, BK=64) + fused attention dots ----------------
// C[M,N] = A[M,K] @ Bt[N,K]^T, plus es/ed[row,h] = sum_c C[row, h*64+c] * a{src,dst}[h,c]
// computed from f32 acc in the epilogue (each (row,head) owned by exactly one wave).
template<int KDIM>
__global__ __launch_bounds__(256) void gemm1_f16(const ushort* __restrict__ A,
                                                 const ushort* __restrict__ Bt,
                                                 ushort* __restrict__ C,
                                                 const float* __restrict__ a_src,
                                                 const float* __restrict__ a_dst,
                                                 float* __restrict__ es,
                                                 float* __restrict__ ed,
                                                 int M, int N) {
    __shared__ __align__(16) ushort Asl[128 * 64];
    __shared__ __align__(16) ushort Bsl[128 * 64];
    const int tid  = threadIdx.x;
    const int lane = tid & 63;
    const int wid  = tid >> 6;
    const int wr   = wid >> 1, wc = wid & 1;
    const int fr   = lane & 15, fq = lane >> 4;
    const int m0   = blockIdx.x * 128;
    const int n0   = blockIdx.y * 128;

    f32x4 acc[4][4] = {};
    const int gcol = (((lane & 7) ^ ((lane >> 3) & 7))) * 8;

    for (int k0 = 0; k0 < KDIM; k0 += 64) {
        __syncthreads();
        #pragma unroll
        for (int i = 0; i < 4; ++i) {
            int chunk = wid * 4 + i;
            int r = chunk * 8 + (lane >> 3);
            const ushort* ga = A  + (size_t)(m0 + r) * KDIM + k0 + gcol;
            const ushort* gb = Bt + (size_t)(n0 + r) * KDIM + k0 + gcol;
            __builtin_amdgcn_global_load_lds(
                (const __attribute__((address_space(1))) void*)ga,
                (__attribute__((address_space(3))) void*)(Asl + chunk * 512), 16, 0, 0);
            __builtin_amdgcn_global_load_lds(
                (const __attribute__((address_space(1))) void*)gb,
                (__attribute__((address_space(3))) void*)(Bsl + chunk * 512), 16, 0, 0);
        }
        __syncthreads();
        #pragma unroll
        for (int ks = 0; ks < 2; ++ks) {
            short8 a[4], b[4];
            #pragma unroll
            for (int m = 0; m < 4; ++m) {
                int row = wr * 64 + m * 16 + fr;
                int slot = (ks * 4 + fq) ^ (fr & 7);
                a[m] = *(const short8*)&Asl[row * 64 + slot * 8];
            }
            #pragma unroll
            for (int n = 0; n < 4; ++n) {
                int row = wc * 64 + n * 16 + fr;
                int slot = (ks * 4 + fq) ^ (fr & 7);
                b[n] = *(const short8*)&Bsl[row * 64 + slot * 8];
            }
            #pragma unroll
            for (int m = 0; m < 4; ++m)
                #pragma unroll
                for (int n = 0; n < 4; ++n)
                    acc[m][n] = __builtin_amdgcn_mfma_f32_16x16x32_f16(
                        __builtin_bit_cast(half8v, a[m]),
                        __builtin_bit_cast(half8v, b[n]), acc[m][n], 0, 0, 0);
        }
    }
    // C store
    #pragma unroll
    for (int m = 0; m < 4; ++m) {
        #pragma unroll
        for (int r = 0; r < 4; ++r) {
            int row = m0 + wr * 64 + m * 16 + fq * 4 + r;
            if (row >= M) continue;
            #pragma unroll
            for (int n = 0; n < 4; ++n)
                C[(size_t)row * N + n0 + wc * 64 + n * 16 + fr] = f2h_bits(acc[m][n][r]);
        }
    }
    // fused dots: this wave owns head h = (n0 + wc*64)/64 for its 64 rows
    {
        int h = (n0 + wc * 64) >> 6;
        float as[4], ad[4];
        #pragma unroll
        for (int n = 0; n < 4; ++n) {
            as[n] = a_src[h * HID + n * 16 + fr];
            ad[n] = a_dst[h * HID + n * 16 + fr];
        }
        #pragma unroll
        for (int m = 0; m < 4; ++m) {
            #pragma unroll
            for (int r = 0; r < 4; ++r) {
                float s = 0.f, d = 0.f;
                #pragma unroll
                for (int n = 0; n < 4; ++n) {
                    float v = acc[m][n][r];
                    s += v * as[n];
                    d += v * ad[n];
                }
                #pragma unroll
                for (int off = 1; off < 16; off <<= 1) {
                    s += __shfl_xor(s, off);
                    d += __shfl_xor(d, off);
                }
                if (fr == 0) {
                    int row = m0 + wr * 64 + m * 16 + fq * 4 + r;
                    if (row < M) {
                        es[row * NH + h] = s;
                        ed[row * NH + h] = d;
                    }
                }
            }
        }
    }
}

// ---------------- layer-2 GEMM: BM=64, BN=128, BK=64 (occupancy-fixed) ----------------
template<int KDIM>
__global__ __launch_bounds__(256) void gemm2_f16(const ushort* __restrict__ A,
                                                 const ushort* __restrict__ Bt,
                                                 ushort* __restrict__ C,
                                                 int M, int N) {
    __shared__ __align__(16) ushort Asl[64 * 64];    // 8 KB
    __shared__ __align__(16) ushort Bsl[128 * 64];   // 16 KB
    const int tid  = threadIdx.x;
    const int lane = tid & 63;
    const int wid  = tid >> 6;
    const int wr   = wid >> 1, wc = wid & 1;
    const int fr   = lane & 15, fq = lane >> 4;
    const int m0   = blockIdx.x * 64;
    const int n0   = blockIdx.y * 128;

    f32x4 acc[2][4] = {};
    const int gcol = (((lane & 7) ^ ((lane >> 3) & 7))) * 8;

    for (int k0 = 0; k0 < KDIM; k0 += 64) {
        __syncthreads();
        #pragma unroll
        for (int i = 0; i < 2; ++i) {          // A: 8 chunks of 1KB
            int chunk = wid * 2 + i;
            int r = chunk * 8 + (lane >> 3);
            const ushort* ga = A + (size_t)(m0 + r) * KDIM + k0 + gcol;
            __builtin_amdgcn_global_load_lds(
                (const __attribute__((address_space(1))) void*)ga,
                (__attribute__((address_space(3))) void*)(Asl + chunk * 512), 16, 0, 0);
        }
        #pragma unroll
        for (int i = 0; i < 4; ++i) {          // B: 16 chunks of 1KB
            int chunk = wid * 4 + i;
            int r = chunk * 8 + (lane >> 3);
            const ushort* gb = Bt + (size_t)(n0 + r) * KDIM + k0 + gcol;
            __builtin_amdgcn_global_load_lds(
                (const __attribute__((address_space(1))) void*)gb,
                (__attribute__((address_space(3))) void*)(Bsl + chunk * 512), 16, 0, 0);
        }
        __syncthreads();
        #pragma unroll
        for (int ks = 0; ks < 2; ++ks) {
            short8 a[2], b[4];
            #pragma unroll
            for (int m = 0; m < 2; ++m) {
                int row = wr * 32 + m * 16 + fr;
                int slot = (ks * 4 + fq) ^ (fr & 7);
                a[m] = *(const short8*)&Asl[row * 64 + slot * 8];
            }
            #pragma unroll
            for (int n = 0; n < 4; ++n) {
                int row = wc * 64 + n * 16 + fr;
                int slot = (ks * 4 + fq) ^ (fr & 7);
                b[n] = *(const short8*)&Bsl[row * 64 + slot * 8];
            }
            #pragma unroll
            for (int m = 0; m < 2; ++m)
                #pragma unroll
                for (int n = 0; n < 4; ++n)
                    acc[m][n] = __builtin_amdgcn_mfma_f32_16x16x32_f16(
                        __builtin_bit_cast(half8v, a[m]),
                        __builtin_bit_cast(half8v, b[n]), acc[m][n], 0, 0, 0);
        }
    }
    #pragma unroll
    for (int m = 0; m < 2; ++m) {
        #pragma unroll
        for (int r = 0; r < 4; ++r) {
            int row = m0 + wr * 32 + m * 16 + fq * 4 + r;
            if (row >= M) continue;
            #pragma unroll
            for (int n = 0; n < 4; ++n)
                C[(size_t)row * N + n0 + wc * 64 + n * 16 + fr] = f2h_bits(acc[m][n][r]);
        }
    }
}

// ---------------- layer-2 attention dots ----------------
__global__ void dots2(const ushort* __restrict__ h2, const float* __restrict__ a_src,
                      const float* __restrict__ a_dst,
                      float* __restrict__ es, float* __restrict__ ed) {
    int gw   = (blockIdx.x * blockDim.x + threadIdx.x) >> 6;
    int lane = threadIdx.x & 63;
    if (gw >= NNODES) return;
    uint u = *(const uint*)&h2[(size_t)gw * OUTC + lane * 2];
    float x0 = h2f((ushort)(u & 0xffffu)), x1 = h2f((ushort)(u >> 16));
    float s = x0 * a_src[lane * 2] + x1 * a_src[lane * 2 + 1];
    float d = x0 * a_dst[lane * 2] + x1 * a_dst[lane * 2 + 1];
    #pragma unroll
    for (int off = 1; off < 64; off <<= 1) {
        s += __shfl_xor(s, off);
        d += __shfl_xor(d, off);
    }
    if (lane == 0) { es[gw] = s; ed[gw] = d; }
}

// ---------------- layer-1 aggregation ----------------
// 1 wave per node, 4 nodes per 256-block, NO block barriers (wave-private LDS).
#define CAP1 128
__global__ __launch_bounds__(256) void attn1(const ushort* __restrict__ h1,
                                             const float* __restrict__ esrc,
                                             const float* __restrict__ edst,
                                             const int* __restrict__ rs,
                                             const int* __restrict__ csr_src,
                                             const float* __restrict__ b1,
                                             ushort* __restrict__ out1) {
    int t = threadIdx.x, lane = t & 63, w = t >> 6;
    int n = blockIdx.x * 4 + w;
    int beg = rs[n], deg = rs[n + 1] - beg;
    int dcap = min(deg, CAP1);
    __shared__ uint  alpha_sh[4][CAP1][9];   // pad 9: conflict-free e-stride
    __shared__ int   ssrc_sh[4][CAP1];
    uint (*alpha)[9] = alpha_sh[w];
    int* ss = ssrc_sh[w];

    for (int e = lane; e < dcap; e += 64) ss[e] = csr_src[beg + e];

    float4 edA = *(const float4*)&edst[n * NH];
    float4 edB = *(const float4*)&edst[n * NH + 4];
    float mx[8], sm[8];
    #pragma unroll
    for (int h = 0; h < 8; ++h) { mx[h] = -1e30f; sm[h] = 0.f; }

    // pass 1: v, per-lane max (store v bits in alpha)
    for (int e = lane; e < deg; e += 64) {
        int s = (e < CAP1) ? ss[e] : csr_src[beg + e];
        float4 eA = *(const float4*)&esrc[(size_t)s * NH];
        float4 eB = *(const float4*)&esrc[(size_t)s * NH + 4];
        float v[8] = { leaky(eA.x + edA.x), leaky(eA.y + edA.y),
                       leaky(eA.z + edA.z), leaky(eA.w + edA.w),
                       leaky(eB.x + edB.x), leaky(eB.y + edB.y),
                       leaky(eB.z + edB.z), leaky(eB.w + edB.w) };
        #pragma unroll
        for (int h = 0; h < 8; ++h) {
            if (e < CAP1) alpha[e][h] = __float_as_uint(v[h]);
            mx[h] = fmaxf(mx[h], v[h]);
        }
    }
    #pragma unroll
    for (int off = 1; off < 64; off <<= 1)
        #pragma unroll
        for (int h = 0; h < 8; ++h)
            mx[h] = fmaxf(mx[h], __shfl_xor(mx[h], off));

    // pass 2: p = exp(v-m) -> alpha (h2 splat), per-lane sum
    for (int e = lane; e < deg; e += 64) {
        float v[8];
        if (e < CAP1) {
            #pragma unroll
            for (int h = 0; h < 8; ++h) v[h] = __uint_as_float(alpha[e][h]);
        } else {
            int s = csr_src[beg + e];
            float4 eA = *(const float4*)&esrc[(size_t)s * NH];
            float4 eB = *(const float4*)&esrc[(size_t)s * NH + 4];
            v[0] = leaky(eA.x + edA.x); v[1] = leaky(eA.y + edA.y);
            v[2] = leaky(eA.z + edA.z); v[3] = leaky(eA.w + edA.w);
            v[4] = leaky(eB.x + edB.x); v[5] = leaky(eB.y + edB.y);
            v[6] = leaky(eB.z + edB.z); v[7] = leaky(eB.w + edB.w);
        }
        #pragma unroll
        for (int h = 0; h < 8; ++h) {
            float p = __expf(v[h] - mx[h]);
            if (e < CAP1) alpha[e][h] = splat_h2(p);
            sm[h] += p;
        }
    }
    #pragma unroll
    for (int off = 1; off < 64; off <<= 1)
        #pragma unroll
        for (int h = 0; h < 8; ++h)
            sm[h] += __shfl_xor(sm[h], off);

    // per-lane head select via constant-indexed unroll (no dynamic reg index)
    int h = lane >> 3;
    float mm = mx[0], ssv = sm[0], edn = edA.x;
    float edv[8] = { edA.x, edA.y, edA.z, edA.w, edB.x, edB.y, edB.z, edB.w };
    #pragma unroll
    for (int hh = 1; hh < 8; ++hh)
        if (h == hh) { mm = mx[hh]; ssv = sm[hh]; edn = edv[hh]; }
    float ri = 1.f / (ssv + 1e-16f);

    // gather: lane owns channels c0..c0+7
    int c0 = lane * 8;
    half2v aA0 = {}, aA1 = {}, aA2 = {}, aA3 = {};
    half2v aB0 = {}, aB1 = {}, aB2 = {}, aB3 = {};
    int e = 0;
    for (; e + 2 <= dcap; e += 2) {
        int s0i = ss[e], s1i = ss[e + 1];
        uint4 u0 = *(const uint4*)&h1[(size_t)s0i * D1 + c0];
        uint4 u1 = *(const uint4*)&h1[(size_t)s1i * D1 + c0];
        half2v p0 = as_h2(alpha[e][h]);
        half2v p1 = as_h2(alpha[e + 1][h]);
        aA0 = as_h2(u0.x) * p0 + aA0; aA1 = as_h2(u0.y) * p0 + aA1;
        aA2 = as_h2(u0.z) * p0 + aA2; aA3 = as_h2(u0.w) * p0 + aA3;
        aB0 = as_h2(u1.x) * p1 + aB0; aB1 = as_h2(u1.y) * p1 + aB1;
        aB2 = as_h2(u1.z) * p1 + aB2; aB3 = as_h2(u1.w) * p1 + aB3;
    }
    for (; e < dcap; ++e) {
        int s = ss[e];
        uint4 u = *(const uint4*)&h1[(size_t)s * D1 + c0];
        half2v p = as_h2(alpha[e][h]);
        aA0 = as_h2(u.x) * p + aA0; aA1 = as_h2(u.y) * p + aA1;
        aA2 = as_h2(u.z) * p + aA2; aA3 = as_h2(u.w) * p + aA3;
    }
    for (; e < deg; ++e) {   // overflow (deg > CAP1)
        int s = csr_src[beg + e];
        float p = __expf(leaky(esrc[(size_t)s * NH + h] + edn) - mm);
        half2v ph = as_h2(splat_h2(p));
        uint4 u = *(const uint4*)&h1[(size_t)s * D1 + c0];
        aA0 = as_h2(u.x) * ph + aA0; aA1 = as_h2(u.y) * ph + aA1;
        aA2 = as_h2(u.z) * ph + aA2; aA3 = as_h2(u.w) * ph + aA3;
    }
    float4 bb0 = *(const float4*)&b1[c0];
    float4 bb1 = *(const float4*)&b1[c0 + 4];
    float o0 = fmaxf(((float)aA0[0] + (float)aB0[0]) * ri + bb0.x, 0.f);
    float o1 = fmaxf(((float)aA0[1] + (float)aB0[1]) * ri + bb0.y, 0.f);
    float o2 = fmaxf(((float)aA1[0] + (float)aB1[0]) * ri + bb0.z, 0.f);
    float o3 = fmaxf(((float)aA1[1] + (float)aB1[1]) * ri + bb0.w, 0.f);
    float o4 = fmaxf(((float)aA2[0] + (float)aB2[0]) * ri + bb1.x, 0.f);
    float o5 = fmaxf(((float)aA2[1] + (float)aB2[1]) * ri + bb1.y, 0.f);
    float o6 = fmaxf(((float)aA3[0] + (float)aB3[0]) * ri + bb1.z, 0.f);
    float o7 = fmaxf(((float)aA3[1] + (float)aB3[1]) * ri + bb1.w, 0.f);
    uint4 pk;
    pk.x = (uint)f2h_bits(o0) | ((uint)f2h_bits(o1) << 16);
    pk.y = (uint)f2h_bits(o2) | ((uint)f2h_bits(o3) << 16);
    pk.z = (uint)f2h_bits(o4) | ((uint)f2h_bits(o5) << 16);
    pk.w = (uint)f2h_bits(o6) | ((uint)f2h_bits(o7) << 16);
    *(uint4*)&out1[(size_t)n * D1 + c0] = pk;
}

// ---------------- layer-2 aggregation ----------------
#define CAP2 128
__global__ __launch_bounds__(256) void attn2(const ushort* __restrict__ h2,
                                             const float* __restrict__ esrc,
                                             const float* __restrict__ edst,
                                             const int* __restrict__ rs,
                                             const int* __restrict__ csr_src,
                                             const float* __restrict__ b2,
                                             float* __restrict__ out) {
    int t = threadIdx.x;
    int g = t >> 5, lane32 = t & 31;
    int n = blockIdx.x * 8 + g;
    if (n >= NNODES) return;
    int beg = rs[n], deg = rs[n + 1] - beg;
    int dcap = min(deg, CAP2);
    __shared__ float al_sh[8][CAP2];
    __shared__ int   ss_sh[8][CAP2];
    float* al = al_sh[g];
    int*   ss = ss_sh[g];

    for (int e = lane32; e < dcap; e += 32) ss[e] = csr_src[beg + e];

    float edn = edst[n];
    float m = -1e30f;
    for (int e = lane32; e < deg; e += 32) {
        int s = (e < CAP2) ? ss[e] : csr_src[beg + e];
        float v = leaky(esrc[s] + edn);
        if (e < CAP2) al[e] = v;
        m = fmaxf(m, v);
    }
    #pragma unroll
    for (int off = 16; off; off >>= 1) m = fmaxf(m, __shfl_xor(m, off));
    float ssum = 0.f;
    for (int e = lane32; e < deg; e += 32) {
        float v = (e < CAP2) ? al[e] : leaky(esrc[csr_src[beg + e]] + edn);
        float p = __expf(v - m);
        if (e < CAP2) *(uint*)&al[e] = splat_h2(p);
        ssum += p;
    }
    #pragma unroll
    for (int off = 16; off; off >>= 1) ssum += __shfl_xor(ssum, off);
    float ri = 1.f / (ssum + 1e-16f);

    int c0 = lane32 * 4;
    half2v a01 = {}, a01b = {}, a23 = {}, a23b = {};
    int e = 0;
    for (; e + 4 <= dcap; e += 4) {
        int s0i = ss[e], s1i = ss[e + 1], s2i = ss[e + 2], s3i = ss[e + 3];
        uint2 u0 = *(const uint2*)&h2[(size_t)s0i * OUTC + c0];
        uint2 u1 = *(const uint2*)&h2[(size_t)s1i * OUTC + c0];
        uint2 u2 = *(const uint2*)&h2[(size_t)s2i * OUTC + c0];
        uint2 u3 = *(const uint2*)&h2[(size_t)s3i * OUTC + c0];
        half2v p0 = as_h2(*(const uint*)&al[e]);
        half2v p1 = as_h2(*(const uint*)&al[e + 1]);
        half2v p2 = as_h2(*(const uint*)&al[e + 2]);
        half2v p3 = as_h2(*(const uint*)&al[e + 3]);
        a01  = as_h2(u0.x) * p0 + a01;  a23  = as_h2(u0.y) * p0 + a23;
        a01b = as_h2(u1.x) * p1 + a01b; a23b = as_h2(u1.y) * p1 + a23b;
        a01  = as_h2(u2.x) * p2 + a01;  a23  = as_h2(u2.y) * p2 + a23;
        a01b = as_h2(u3.x) * p3 + a01b; a23b = as_h2(u3.y) * p3 + a23b;
    }
    for (; e < dcap; ++e) {
        int s = ss[e];
        uint2 u = *(const uint2*)&h2[(size_t)s * OUTC + c0];
        half2v p = as_h2(*(const uint*)&al[e]);
        a01 = as_h2(u.x) * p + a01;
        a23 = as_h2(u.y) * p + a23;
    }
    for (; e < deg; ++e) {
        int s = csr_src[beg + e];
        float p = __expf(leaky(esrc[s] + edn) - m);
        half2v ph = as_h2(splat_h2(p));
        uint2 u = *(const uint2*)&h2[(size_t)s * OUTC + c0];
        a01 = as_h2(u.x) * ph + a01;
        a23 = as_h2(u.y) * ph + a23;
    }
    float4 bb = *(const float4*)&b2[c0];
    float4 o;
    o.x = ((float)a01[0] + (float)a01b[0]) * ri + bb.x;
    o.y = ((float)a01[1] + (float)a01b[1]) * ri + bb.y;
    o.z = ((float)a23[0] + (float)a23b[0]) * ri + bb.z;
    o.w = ((float)a23[1] + (float)a23b[1]) * ri + bb.w;
    *(float4*)&out[(size_t)n * OUTC + c0] = o;
}

// ---------------- launch ----------------
extern "C" void kernel_launch(void* const* d_in, const int* in_sizes, int n_in,
                              void* d_out, int out_size, void* d_ws, size_t ws_size,
                              hipStream_t stream) {
    const float* x   = (const float*)d_in[0];
    const int*   ei  = (const int*)  d_in[1];
    const float* W1  = (const float*)d_in[2];
    const float* b1  = (const float*)d_in[3];
    const float* as1 = (const float*)d_in[4];
    const float* ad1 = (const float*)d_in[5];
    const float* W2  = (const float*)d_in[6];
    const float* b2  = (const float*)d_in[7];
    const float* as2 = (const float*)d_in[8];
    const float* ad2 = (const float*)d_in[9];
    float* out = (float*)d_out;

    char* ws = (char*)d_ws;
    size_t off = 0;
    auto alloc = [&](size_t bytes) -> void* {
        void* p = ws + off;
        off = (off + bytes + 255) & ~(size_t)255;
        return p;
    };
    ushort* xh    = (ushort*)alloc((size_t)MPAD * INC * 2);
    ushort* w1t   = (ushort*)alloc((size_t)D1 * INC * 2);
    ushort* w2t   = (ushort*)alloc((size_t)OUTC * D1 * 2);
    ushort* h1h   = (ushort*)alloc((size_t)MPAD * D1 * 2);
    ushort* out1h = (ushort*)alloc((size_t)MPAD * D1 * 2);
    ushort* h2h   = (ushort*)alloc((size_t)MPAD * OUTC * 2);
    float*  es1   = (float*)alloc((size_t)NNODES * NH * 4);
    float*  ed1   = (float*)alloc((size_t)NNODES * NH * 4);
    float*  es2   = (float*)alloc((size_t)NNODES * 4);
    float*  ed2   = (float*)alloc((size_t)NNODES * 4);
    int*    deg   = (int*)alloc((size_t)NNODES * 4);
    int*    rs    = (int*)alloc((size_t)(NNODES + 1) * 4);
    int*    cur   = (int*)alloc((size_t)NNODES * 4);
    int*    csr   = (int*)alloc((size_t)ETOT * 4);

    // CSR build
    hipMemsetAsync(deg, 0, (size_t)NNODES * 4, stream);
    count_deg<<<(ETOT + 255) / 256, 256, 0, stream>>>(ei, deg);
    scan_deg<<<1, 1024, 0, stream>>>(deg, rs);
    hipMemcpyAsync(cur, rs, (size_t)NNODES * 4, hipMemcpyDeviceToDevice, stream);
    scatter_edges<<<(ETOT + 255) / 256, 256, 0, stream>>>(ei, cur, csr);

    // dtype prep
    cast_f16<<<(NNODES * INC / 4 + 255) / 256, 256, 0, stream>>>(x, xh, NNODES * INC / 4);
    cast_wT<<<(INC * D1 + 255) / 256, 256, 0, stream>>>(W1, w1t, INC, D1);
    cast_wT<<<(D1 * OUTC + 255) / 256, 256, 0, stream>>>(W2, w2t, D1, OUTC);

    // layer 1 (GEMM + fused dots)
    gemm1_f16<INC><<<dim3(MPAD / 128, D1 / 128), 256, 0, stream>>>(
        xh, w1t, h1h, as1, ad1, es1, ed1, NNODES, D1);
    attn1<<<NNODES / 4, 256, 0, stream>>>(h1h, es1, ed1, rs, csr, b1, out1h);

    // layer 2
    gemm2_f16<D1><<<dim3(MPAD / 64, OUTC / 128), 256, 0, stream>>>(out1h, w2t, h2h, NNODES, OUTC);
    dots2<<<(NNODES * 64 + 255) / 256, 256, 0, stream>>>(h2h, as2, ad2, es2, ed2);
    attn2<<<NNODES / 8, 256, 0, stream>>>(h2h, es2, ed2, rs, csr, b2, out);
}